// Round 1
// baseline (2074.615 us; speedup 1.0000x reference)
//
#include <hip/hip_runtime.h>
#include <hip/hip_bf16.h>

typedef __attribute__((ext_vector_type(8))) short short8;
typedef __attribute__((ext_vector_type(4))) float f32x4;

#define DDIM 256
#define BM   64
#define LDSK 264   // bf16 elements per LDS row: 256 + 8 pad -> 2-way (free) ds_read_b128 conflicts

// ---- prep: W fp32 [n][k] -> bf16 [n][k] (this IS the MFMA B-operand layout for emb @ W.T) ----
__global__ __launch_bounds__(256) void wprep_kernel(const float* __restrict__ W,
                                                    ushort* __restrict__ Wb) {
    int idx = blockIdx.x * 256 + threadIdx.x;   // 65536 threads, 1 elem each
    __hip_bfloat16 h = __float2bfloat16(W[idx]);
    Wb[idx] = *reinterpret_cast<ushort*>(&h);
}

__global__ __launch_bounds__(256) void relupd_kernel(
    const float*  __restrict__ emb,
    const int*    __restrict__ ntype,
    const ushort* __restrict__ Wb,
    const float*  __restrict__ bias,
    float*        __restrict__ out)
{
    __shared__ ushort As[BM * LDSK];   // 33792 B

    const int tid  = threadIdx.x;
    const int lane = tid & 63;
    const int wave = tid >> 6;
    const int m    = lane & 15;        // col within 16x16 tile (C), row within A-frag
    const int quad = lane >> 4;
    const size_t rowblock = (size_t)blockIdx.x * BM;

    // ---- stage A tile: 64 rows x 256 k, fp32 -> bf16 LDS (tile is one contiguous 64KB chunk) ----
    const float* src = emb + rowblock * DDIM;
    #pragma unroll
    for (int r = 0; r < 8; ++r) {
        const int flat = (r * 256 + tid) * 8;       // 8 consecutive floats per thread per round
        const int row  = flat >> 8;
        const int k    = flat & 255;
        f32x4 f0 = *reinterpret_cast<const f32x4*>(src + flat);
        f32x4 f1 = *reinterpret_cast<const f32x4*>(src + flat + 4);
        union { short8 v; ushort u[8]; } pk;
        #pragma unroll
        for (int i = 0; i < 4; ++i) {
            __hip_bfloat16 h0 = __float2bfloat16(f0[i]);
            __hip_bfloat16 h1 = __float2bfloat16(f1[i]);
            pk.u[i]     = *reinterpret_cast<ushort*>(&h0);
            pk.u[i + 4] = *reinterpret_cast<ushort*>(&h1);
        }
        *reinterpret_cast<short8*>(&As[row * LDSK + k]) = pk.v;  // 16B aligned: 264*2=528=16*33, k%8==0
    }
    __syncthreads();

    // ---- MFMA: wave w computes rows 0..63 x cols [w*64, w*64+64) ----
    const int colbase = wave * 64;

    float bv[4];
    #pragma unroll
    for (int ct = 0; ct < 4; ++ct) bv[ct] = bias[colbase + ct * 16 + m];

    f32x4 acc[4][4];
    #pragma unroll
    for (int rt = 0; rt < 4; ++rt)
        #pragma unroll
        for (int ct = 0; ct < 4; ++ct)
            acc[rt][ct] = (f32x4)(0.0f);

    #pragma unroll
    for (int ks = 0; ks < 8; ++ks) {
        // A-frag: A[m = lane&15][k = quad*8 + j]
        short8 a[4];
        #pragma unroll
        for (int rt = 0; rt < 4; ++rt)
            a[rt] = *reinterpret_cast<const short8*>(&As[(rt * 16 + m) * LDSK + ks * 32 + quad * 8]);
        #pragma unroll
        for (int ct = 0; ct < 4; ++ct) {
            // B-frag: B[k = quad*8+j][n = lane&15] = W[n][k] -> contiguous k in row-major Wb
            short8 bf = *reinterpret_cast<const short8*>(
                Wb + (size_t)(colbase + ct * 16 + m) * DDIM + ks * 32 + quad * 8);
            #pragma unroll
            for (int rt = 0; rt < 4; ++rt)
                acc[rt][ct] = __builtin_amdgcn_mfma_f32_16x16x32_bf16(a[rt], bf, acc[rt][ct], 0, 0, 0);
        }
    }

    // ---- epilogue: C/D layout col = lane&15, row = quad*4 + reg; fuse +b and per-row select ----
    #pragma unroll
    for (int rt = 0; rt < 4; ++rt) {
        #pragma unroll
        for (int reg = 0; reg < 4; ++reg) {
            const size_t row = rowblock + rt * 16 + quad * 4 + reg;
            const int t = ntype[row];
            #pragma unroll
            for (int ct = 0; ct < 4; ++ct) {
                const int col = colbase + ct * 16 + m;
                float v;
                if (t == 1) v = acc[rt][ct][reg] + bv[ct];
                else        v = emb[row * DDIM + col];   // tile just streamed -> L2 hit
                out[row * DDIM + col] = v;
            }
        }
    }
}

extern "C" void kernel_launch(void* const* d_in, const int* in_sizes, int n_in,
                              void* d_out, int out_size, void* d_ws, size_t ws_size,
                              hipStream_t stream) {
    const float*  emb  = (const float*)d_in[0];
    const int*    ntyp = (const int*)d_in[1];
    const float*  W    = (const float*)d_in[2];
    const float*  bias = (const float*)d_in[3];
    float* out = (float*)d_out;
    ushort* Wb = (ushort*)d_ws;   // 128 KB scratch for bf16 W

    wprep_kernel<<<(DDIM * DDIM) / 256, 256, 0, stream>>>(W, Wb);

    const int N = in_sizes[1];            // 1,000,000 (divisible by BM=64: 15625 blocks, no tail)
    const int nblocks = (N + BM - 1) / BM;
    relupd_kernel<<<nblocks, 256, 0, stream>>>(emb, ntyp, Wb, bias, out);
}